// Round 14
// baseline (356.703 us; speedup 1.0000x reference)
//
#include <hip/hip_runtime.h>

#define N_NODES 50000
#define N_EDGES 600000
#define DH 128
#define BN_EPS 1e-5f
#define SCAN_BLOCKS ((N_NODES + 255) / 256)   // 196
#define HEAD_GRID ((N_NODES + 63) / 64)       // 782

typedef __attribute__((ext_vector_type(8))) short bf16x8;
typedef __attribute__((ext_vector_type(4))) float f32x4;

// round-to-nearest-even fp32 -> bf16 (bit trick, sign-safe)
__device__ inline unsigned short f2bf(float x) {
  unsigned u = __float_as_uint(x);
  return (unsigned short)((u + 0x7FFFu + ((u >> 16) & 1u)) >> 16);
}
__device__ inline float bf2f(unsigned short h) {
  return __uint_as_float(((unsigned)h) << 16);
}

// async global->LDS, 16 B per lane: lane i's data lands at lds_base + i*16.
__device__ inline void gl_lds16(const unsigned short* g, unsigned short* l) {
  __builtin_amdgcn_global_load_lds(
      (const __attribute__((address_space(1))) unsigned int*)g,
      (__attribute__((address_space(3))) unsigned int*)l, 16, 0, 0);
}

// ---------------------------------------------------------------------------
// Fused weight pre-split + edge-degree count (block-range fusion) + dummy-row
// zero for BOTH feature ping-pong buffers (block 0 rides along).
// Column-slot permutation: output col n placed so the epilogue lane's 4
// c-values are CONTIGUOUS output columns (colbase = ch*64 + coln*4 + c):
//   slot ct = (n>>6)*4 + (n&3), slot coln = (n>>2)&15
// k-mapping: plane[((kstep32*8 + ctile)*64 + lane)*8 + j],
// k = kstep32*32 + (lane>>4)*8 + j. W split hi/lo (Wh+Wl == W to 2^-17).
// ---------------------------------------------------------------------------
__global__ __launch_bounds__(256) void convert_W5_count(
    const float* __restrict__ hW, const float* __restrict__ g1,
    const float* __restrict__ l1, const float* __restrict__ g2,
    const float* __restrict__ l2,
    unsigned short* __restrict__ hH, unsigned short* __restrict__ hL,
    unsigned short* __restrict__ g1H, unsigned short* __restrict__ g1L,
    unsigned short* __restrict__ l1H, unsigned short* __restrict__ l1L,
    unsigned short* __restrict__ g2H, unsigned short* __restrict__ g2L,
    unsigned short* __restrict__ l2H, unsigned short* __restrict__ l2L,
    const int* __restrict__ eidx, int* __restrict__ cnt,
    unsigned* __restrict__ dummy0, unsigned* __restrict__ dummy1) {
  int b = blockIdx.x;
  if (b >= 512) {
    int e = (b - 512) * 256 + threadIdx.x;
    if (e < N_EDGES) atomicAdd(&cnt[eidx[N_EDGES + e]], 1);
    return;
  }
  if (b == 0 && threadIdx.x < 64) {
    dummy0[threadIdx.x] = 0u;   // 128 bf16 zeros each
    dummy1[threadIdx.x] = 0u;
  }
  const float* W;
  unsigned short *hi, *lo;
  int idx;
  if (b < 256) {
    W = hW; hi = hH; lo = hL;
    idx = b * 256 + threadIdx.x;
  } else {
    int w = (b - 256) >> 6;
    idx = ((b - 256) & 63) * 256 + threadIdx.x;
    W = (w == 0) ? g1 : (w == 1) ? l1 : (w == 2) ? g2 : l2;
    hi = (w == 0) ? g1H : (w == 1) ? l1H : (w == 2) ? g2H : l2H;
    lo = (w == 0) ? g1L : (w == 1) ? l1L : (w == 2) ? g2L : l2L;
  }
  int k = idx >> 7;
  int n = idx & 127;
  float x = W[idx];
  unsigned short h = f2bf(x);
  unsigned short l = f2bf(x - bf2f(h));
  int kstep = k >> 5;
  int ctile = ((n >> 6) << 2) | (n & 3);
  int cs = (n >> 2) & 15;
  int lane = ((k >> 3) & 3) * 16 + cs;
  int j = k & 7;
  size_t off = ((size_t)(kstep * 8 + ctile) * 64 + lane) * 8 + j;
  hi[off] = h;
  lo[off] = l;
}

// ---------------------------------------------------------------------------
// Head GEMM (K=512) — proven form + fused fill_csr; bf16-only output (fp32 X
// dropped pipeline-wide, R10). BM=64, BK=64, 2 barriers/kstep. LDS ~41 KB.
// ---------------------------------------------------------------------------
__global__ __launch_bounds__(256) void gemm_head_fill(
    const float* __restrict__ A,
    const unsigned short* __restrict__ Bh, const unsigned short* __restrict__ Bl,
    const float* __restrict__ bias,
    unsigned short* __restrict__ xb_out, int M,
    const int* __restrict__ eidx, const int* __restrict__ rs,
    int* __restrict__ cursor, int* __restrict__ esrc) {
  constexpr int K = 512;
  constexpr int KSTEPS = K / 64;
  constexpr int ASTR = 72;  // 64 k + 8 pad (2-way bank alias = free)
  __shared__ __align__(16) unsigned short Ah[64 * ASTR];   // 9.2 KB
  __shared__ __align__(16) unsigned short Bhs[2][4096];    // 16 KB
  __shared__ __align__(16) unsigned short Bls[2][4096];    // 16 KB

  if (blockIdx.x >= HEAD_GRID) {
    // ---- fill_csr part: scatter edge sources into CSR slots ----
    int e = (blockIdx.x - HEAD_GRID) * 256 + threadIdx.x;
    if (e < N_EDGES) {
      int d = eidx[N_EDGES + e];
      int p = atomicAdd(&cursor[d], 1);
      esrc[rs[d] + p] = eidx[e];
    }
    return;
  }

  const int tid = threadIdx.x;
  const int wave = tid >> 6;
  const int lane = tid & 63;
  const int m0 = blockIdx.x * 64;

  // A staging: thread owns row tid>>2 (0..63), 16-elem group tid&3
  const int s_row = tid >> 2;
  const int s_grp = tid & 3;
  const int g_row = m0 + s_row;
  const int g_rowc = (g_row < M) ? g_row : (M - 1);
  const float* af = A + (size_t)g_rowc * K + s_grp * 16;

  const int rgrp = wave & 1;  // 32-row group
  const int ch = wave >> 1;   // 64-col half

  f32x4 acc[2][4];
#pragma unroll
  for (int r = 0; r < 2; ++r)
#pragma unroll
    for (int c = 0; c < 4; ++c) acc[r][c] = (f32x4){0.f, 0.f, 0.f, 0.f};

  for (int ks = 0; ks < KSTEPS; ++ks) {
    // ---- stage A (64 rows x 64 k fp32 -> bf16) ----
    {
      float4 f0 = *(const float4*)(af + ks * 64);
      float4 f1 = *(const float4*)(af + ks * 64 + 4);
      float4 f2 = *(const float4*)(af + ks * 64 + 8);
      float4 f3 = *(const float4*)(af + ks * 64 + 12);
      ushort4 h0, h1, h2, h3;
      h0.x = f2bf(f0.x); h0.y = f2bf(f0.y); h0.z = f2bf(f0.z); h0.w = f2bf(f0.w);
      h1.x = f2bf(f1.x); h1.y = f2bf(f1.y); h1.z = f2bf(f1.z); h1.w = f2bf(f1.w);
      h2.x = f2bf(f2.x); h2.y = f2bf(f2.y); h2.z = f2bf(f2.z); h2.w = f2bf(f2.w);
      h3.x = f2bf(f3.x); h3.y = f2bf(f3.y); h3.z = f2bf(f3.z); h3.w = f2bf(f3.w);
      int base = s_row * ASTR + s_grp * 16;
      *(ushort4*)&Ah[base + 0] = h0;
      *(ushort4*)&Ah[base + 4] = h1;
      *(ushort4*)&Ah[base + 8] = h2;
      *(ushort4*)&Ah[base + 12] = h3;
    }
    // ---- stage B: two 32-k sub-steps, 8 KB per plane each ----
#pragma unroll
    for (int s = 0; s < 2; ++s) {
      const unsigned short* sh = Bh + (size_t)(2 * ks + s) * 4096 + wave * 1024;
      const unsigned short* sl = Bl + (size_t)(2 * ks + s) * 4096 + wave * 1024;
      gl_lds16(sh + lane * 8, &Bhs[s][wave * 1024]);
      gl_lds16(sh + 512 + lane * 8, &Bhs[s][wave * 1024 + 512]);
      gl_lds16(sl + lane * 8, &Bls[s][wave * 1024]);
      gl_lds16(sl + 512 + lane * 8, &Bls[s][wave * 1024 + 512]);
    }
    __syncthreads();

    // ---- compute: 2 k-chunks x 4 c-tiles x (hi+lo) x 2 row-frags ----
#pragma unroll
    for (int s = 0; s < 2; ++s) {
      bf16x8 a0 = *(const bf16x8*)&Ah[(rgrp * 32 + (lane & 15)) * ASTR + s * 32 + (lane >> 4) * 8];
      bf16x8 a1 = *(const bf16x8*)&Ah[(rgrp * 32 + 16 + (lane & 15)) * ASTR + s * 32 + (lane >> 4) * 8];
#pragma unroll
      for (int c = 0; c < 4; ++c) {
        int ct = ch * 4 + c;
        bf16x8 bh = *(const bf16x8*)&Bhs[s][(ct * 64 + lane) * 8];
        bf16x8 bl = *(const bf16x8*)&Bls[s][(ct * 64 + lane) * 8];
        acc[0][c] = __builtin_amdgcn_mfma_f32_16x16x32_bf16(a0, bh, acc[0][c], 0, 0, 0);
        acc[0][c] = __builtin_amdgcn_mfma_f32_16x16x32_bf16(a0, bl, acc[0][c], 0, 0, 0);
        acc[1][c] = __builtin_amdgcn_mfma_f32_16x16x32_bf16(a1, bh, acc[1][c], 0, 0, 0);
        acc[1][c] = __builtin_amdgcn_mfma_f32_16x16x32_bf16(a1, bl, acc[1][c], 0, 0, 0);
      }
    }
    __syncthreads();
  }

  // ---- epilogue: bf16 mirror only (slot c = output col colbase+c) ----
  const int coln = lane & 15;
  const int rown = (lane >> 4) * 4;
  const int colbase = ch * 64 + coln * 4;
  const float4 bv = *(const float4*)(bias + colbase);
#pragma unroll
  for (int r = 0; r < 2; ++r) {
#pragma unroll
    for (int reg = 0; reg < 4; ++reg) {
      int row = m0 + rgrp * 32 + r * 16 + rown + reg;
      if (row < M) {
        ushort4 hb;
        hb.x = f2bf(fmaxf(acc[r][0][reg] + bv.x, 0.f));
        hb.y = f2bf(fmaxf(acc[r][1][reg] + bv.y, 0.f));
        hb.z = f2bf(fmaxf(acc[r][2][reg] + bv.z, 0.f));
        hb.w = f2bf(fmaxf(acc[r][3][reg] + bv.w, 0.f));
        *(ushort4*)&xb_out[(size_t)row * DH + colbase] = hb;
      }
    }
  }
}

// ---------------------------------------------------------------------------
// FUSED aggregate + GIN MLP pair. R13: R12's 4-threads-per-node gather with
// the ROW-STRIDE FIX: a feature row is 128 bf16 = 16 uint4 (R12 used 32 ->
// read wrong rows, absmax 4.47). tid>>2 = local node, tid&3 = 32-dim
// quarter; each thread walks one node's padded edge list in 4-edge batches
// with 16 unrolled uint4 gathers in flight -> serial depth ~6-8 (vs R11's
// ~48 dependent rounds/wave).
// Stage 1 reads y from Hb; stage 2 overwrites Hb with h (barrier-ordered).
// Epilogue: layer 1 -> xb_out bf16; layer 2 -> fused tail (z + BN partials).
// LDS: 8 + 8 + 17.4 = 33.4 KB -> 4 blocks/CU.
// ---------------------------------------------------------------------------
__global__ __launch_bounds__(256) void gemm_gin_fused(
    const unsigned short* __restrict__ xb_in,
    const int* __restrict__ rs, const int* __restrict__ esrc,
    const unsigned short* __restrict__ B1h, const unsigned short* __restrict__ B1l,
    const float* __restrict__ b1,
    const unsigned short* __restrict__ B2h, const unsigned short* __restrict__ B2l,
    const float* __restrict__ b2,
    unsigned short* __restrict__ xb_out, int M,
    const float* __restrict__ tw, const float* __restrict__ tb,
    float* __restrict__ z, float* __restrict__ red) {
  constexpr int KSTEPS = 4;   // K=128, BK=32
  constexpr int HSTR = 136;   // 128 + 8 pad
  __shared__ __align__(16) unsigned short Bhs[4096];       // 8 KB
  __shared__ __align__(16) unsigned short Bls[4096];       // 8 KB
  __shared__ __align__(16) unsigned short Hb[64 * HSTR];   // 17.4 KB (y, then h)

  const int tid = threadIdx.x;
  const int wave = tid >> 6;
  const int lane = tid & 63;
  const int m0 = blockIdx.x * 64;

  const int rgrp = wave & 1;
  const int ch = wave >> 1;
  const int coln = lane & 15;
  const int rown = (lane >> 4) * 4;
  const int colbase = ch * 64 + coln * 4;

  auto issueB = [&](const unsigned short* Bh, const unsigned short* Bl, int ks) {
    const unsigned short* sh = Bh + (size_t)ks * 4096 + wave * 1024;
    const unsigned short* sl = Bl + (size_t)ks * 4096 + wave * 1024;
    gl_lds16(sh + lane * 8, &Bhs[wave * 1024]);
    gl_lds16(sh + 512 + lane * 8, &Bhs[wave * 1024 + 512]);
    gl_lds16(sl + lane * 8, &Bls[wave * 1024]);
    gl_lds16(sl + 512 + lane * 8, &Bls[wave * 1024 + 512]);
  };

  // ---- B1(0) in flight before the gather phase ----
  issueB(B1h, B1l, 0);

  // ================= aggregation phase: y -> Hb (bf16), 4 thr/node =========
  {
    const uint4* xb4 = (const uint4*)xb_in;   // feature row = 16 uint4 (256 B)
    const int lrow = tid >> 2;                // local node 0..63
    const int q = tid & 3;                    // 32-dim quarter
    const int node = m0 + lrow;
    float accq[32];
#pragma unroll
    for (int d = 0; d < 32; ++d) accq[d] = 0.f;

    if (node < M) {
      // ---- self term ----
      {
        const uint4* row = xb4 + (size_t)node * 16 + q * 4;
#pragma unroll
        for (int k = 0; k < 4; ++k) {
          uint4 v = row[k];
          unsigned u0 = v.x, u1 = v.y, u2 = v.z, u3 = v.w;
          accq[k * 8 + 0] = __uint_as_float(u0 << 16);
          accq[k * 8 + 1] = __uint_as_float(u0 & 0xFFFF0000u);
          accq[k * 8 + 2] = __uint_as_float(u1 << 16);
          accq[k * 8 + 3] = __uint_as_float(u1 & 0xFFFF0000u);
          accq[k * 8 + 4] = __uint_as_float(u2 << 16);
          accq[k * 8 + 5] = __uint_as_float(u2 & 0xFFFF0000u);
          accq[k * 8 + 6] = __uint_as_float(u3 << 16);
          accq[k * 8 + 7] = __uint_as_float(u3 & 0xFFFF0000u);
        }
      }
      // ---- neighbor terms: padded list, pure 4-edge batches ----
      int beg = rs[node];
      int end = rs[node + 1];
      for (int j = beg; j < end; j += 4) {
        int4 ia = *(const int4*)&esrc[j];
        const uint4* r0 = xb4 + (size_t)ia.x * 16 + q * 4;
        const uint4* r1 = xb4 + (size_t)ia.y * 16 + q * 4;
        const uint4* r2 = xb4 + (size_t)ia.z * 16 + q * 4;
        const uint4* r3 = xb4 + (size_t)ia.w * 16 + q * 4;
#pragma unroll
        for (int k = 0; k < 4; ++k) {
          uint4 v0 = r0[k];
          uint4 v1 = r1[k];
          uint4 v2 = r2[k];
          uint4 v3 = r3[k];
          unsigned a0[4] = {v0.x, v0.y, v0.z, v0.w};
          unsigned a1[4] = {v1.x, v1.y, v1.z, v1.w};
          unsigned a2[4] = {v2.x, v2.y, v2.z, v2.w};
          unsigned a3[4] = {v3.x, v3.y, v3.z, v3.w};
#pragma unroll
          for (int t = 0; t < 4; ++t) {
            accq[k * 8 + 2 * t] +=
                (__uint_as_float(a0[t] << 16) + __uint_as_float(a1[t] << 16)) +
                (__uint_as_float(a2[t] << 16) + __uint_as_float(a3[t] << 16));
            accq[k * 8 + 2 * t + 1] +=
                (__uint_as_float(a0[t] & 0xFFFF0000u) + __uint_as_float(a1[t] & 0xFFFF0000u)) +
                (__uint_as_float(a2[t] & 0xFFFF0000u) + __uint_as_float(a3[t] & 0xFFFF0000u));
          }
        }
      }
    }
    // ---- pack + write my 32 dims (4 aligned uint4 stores) ----
    uint4* dst = (uint4*)&Hb[lrow * HSTR + q * 32];
#pragma unroll
    for (int k = 0; k < 4; ++k) {
      uint4 o;
      o.x = (unsigned)f2bf(accq[k * 8 + 0]) | ((unsigned)f2bf(accq[k * 8 + 1]) << 16);
      o.y = (unsigned)f2bf(accq[k * 8 + 2]) | ((unsigned)f2bf(accq[k * 8 + 3]) << 16);
      o.z = (unsigned)f2bf(accq[k * 8 + 4]) | ((unsigned)f2bf(accq[k * 8 + 5]) << 16);
      o.w = (unsigned)f2bf(accq[k * 8 + 6]) | ((unsigned)f2bf(accq[k * 8 + 7]) << 16);
      dst[k] = o;
    }
  }

  f32x4 acc[2][4];
#pragma unroll
  for (int r = 0; r < 2; ++r)
#pragma unroll
    for (int c = 0; c < 4; ++c) acc[r][c] = (f32x4){0.f, 0.f, 0.f, 0.f};

  // ================= stage 1: h = relu(y @ W1 + b1) =================
  for (int ks = 0; ks < KSTEPS; ++ks) {
    if (ks > 0) issueB(B1h, B1l, ks);
    __syncthreads();  // iter 0: publishes Hb (y) + B1(0)
    bf16x8 a0 = *(const bf16x8*)&Hb[(rgrp * 32 + (lane & 15)) * HSTR + ks * 32 + (lane >> 4) * 8];
    bf16x8 a1 = *(const bf16x8*)&Hb[(rgrp * 32 + 16 + (lane & 15)) * HSTR + ks * 32 + (lane >> 4) * 8];
#pragma unroll
    for (int c = 0; c < 4; ++c) {
      int ct = ch * 4 + c;
      bf16x8 bh = *(const bf16x8*)&Bhs[(ct * 64 + lane) * 8];
      bf16x8 bl = *(const bf16x8*)&Bls[(ct * 64 + lane) * 8];
      acc[0][c] = __builtin_amdgcn_mfma_f32_16x16x32_bf16(a0, bh, acc[0][c], 0, 0, 0);
      acc[0][c] = __builtin_amdgcn_mfma_f32_16x16x32_bf16(a0, bl, acc[0][c], 0, 0, 0);
      acc[1][c] = __builtin_amdgcn_mfma_f32_16x16x32_bf16(a1, bh, acc[1][c], 0, 0, 0);
      acc[1][c] = __builtin_amdgcn_mfma_f32_16x16x32_bf16(a1, bl, acc[1][c], 0, 0, 0);
    }
    __syncthreads();
  }

  // ---- h -> Hb (overwrites y; all stage-1 reads completed at last barrier) ----
  {
    const float4 bv = *(const float4*)(b1 + colbase);
#pragma unroll
    for (int r = 0; r < 2; ++r) {
#pragma unroll
      for (int reg = 0; reg < 4; ++reg) {
        int lrow = rgrp * 32 + r * 16 + rown + reg;
        ushort4 hb;
        hb.x = f2bf(fmaxf(acc[r][0][reg] + bv.x, 0.f));
        hb.y = f2bf(fmaxf(acc[r][1][reg] + bv.y, 0.f));
        hb.z = f2bf(fmaxf(acc[r][2][reg] + bv.z, 0.f));
        hb.w = f2bf(fmaxf(acc[r][3][reg] + bv.w, 0.f));
        *(ushort4*)&Hb[lrow * HSTR + colbase] = hb;
      }
    }
#pragma unroll
    for (int r = 0; r < 2; ++r)
#pragma unroll
      for (int c = 0; c < 4; ++c) acc[r][c] = (f32x4){0.f, 0.f, 0.f, 0.f};
  }

  // ================= stage 2: out = h @ W2 + b2 =================
  for (int ks = 0; ks < KSTEPS; ++ks) {
    issueB(B2h, B2l, ks);
    __syncthreads();  // first iter: also publishes h to all waves
    bf16x8 a0 = *(const bf16x8*)&Hb[(rgrp * 32 + (lane & 15)) * HSTR + ks * 32 + (lane >> 4) * 8];
    bf16x8 a1 = *(const bf16x8*)&Hb[(rgrp * 32 + 16 + (lane & 15)) * HSTR + ks * 32 + (lane >> 4) * 8];
#pragma unroll
    for (int c = 0; c < 4; ++c) {
      int ct = ch * 4 + c;
      bf16x8 bh = *(const bf16x8*)&Bhs[(ct * 64 + lane) * 8];
      bf16x8 bl = *(const bf16x8*)&Bls[(ct * 64 + lane) * 8];
      acc[0][c] = __builtin_amdgcn_mfma_f32_16x16x32_bf16(a0, bh, acc[0][c], 0, 0, 0);
      acc[0][c] = __builtin_amdgcn_mfma_f32_16x16x32_bf16(a0, bl, acc[0][c], 0, 0, 0);
      acc[1][c] = __builtin_amdgcn_mfma_f32_16x16x32_bf16(a1, bh, acc[1][c], 0, 0, 0);
      acc[1][c] = __builtin_amdgcn_mfma_f32_16x16x32_bf16(a1, bl, acc[1][c], 0, 0, 0);
    }
    __syncthreads();  // last iter: Hb reads complete -> safe to reuse below
  }

  const float4 bv = *(const float4*)(b2 + colbase);

  if (tw == nullptr) {
    // ---- layer-1 epilogue: bf16 features only ----
#pragma unroll
    for (int r = 0; r < 2; ++r) {
#pragma unroll
      for (int reg = 0; reg < 4; ++reg) {
        int row = m0 + rgrp * 32 + r * 16 + rown + reg;
        if (row < M) {
          ushort4 hb;
          hb.x = f2bf(acc[r][0][reg] + bv.x);
          hb.y = f2bf(acc[r][1][reg] + bv.y);
          hb.z = f2bf(acc[r][2][reg] + bv.z);
          hb.w = f2bf(acc[r][3][reg] + bv.w);
          *(ushort4*)&xb_out[(size_t)row * DH + colbase] = hb;
        }
      }
    }
  } else {
    // ---- layer-2 fused-tail epilogue: z + BN partials, no feature write ----
    float* zpart = (float*)Hb;  // 64 x 33 fp32 = 8.4 KB (fits in 17.4 KB)
    const float4 tw4 = *(const float4*)(tw + colbase);
#pragma unroll
    for (int r = 0; r < 2; ++r) {
#pragma unroll
      for (int reg = 0; reg < 4; ++reg) {
        int lrow = rgrp * 32 + r * 16 + rown + reg;
        float4 v;
        v.x = acc[r][0][reg] + bv.x;
        v.y = acc[r][1][reg] + bv.y;
        v.z = acc[r][2][reg] + bv.z;
        v.w = acc[r][3][reg] + bv.w;
        zpart[lrow * 33 + ch * 16 + coln] =
            v.x * tw4.x + v.y * tw4.y + v.z * tw4.z + v.w * tw4.w;
      }
    }
    __syncthreads();
    if (tid < 64) {
      int row = m0 + tid;
      float s = 0.f;
#pragma unroll
      for (int k = 0; k < 32; ++k) s += zpart[tid * 33 + k];
      float zv = s + tb[0];
      bool valid = row < M;
      if (valid) z[row] = zv;
      float a = valid ? zv : 0.f;
      float q = valid ? zv * zv : 0.f;
#pragma unroll
      for (int m = 32; m; m >>= 1) {
        a += __shfl_xor(a, m);
        q += __shfl_xor(q, m);
      }
      if (tid == 0) {
        atomicAdd(&red[0], a);
        atomicAdd(&red[1], q);
      }
    }
  }
}

// ---------------------------------------------------------------------------
// CSR build: exclusive scan over PADDED degrees (pad to multiple of 4 so the
// gather's index loads are aligned int4 and the edge loop has no tails).
// Pad slots point at dummy node N_NODES whose feature rows are zeroed.
// ---------------------------------------------------------------------------
__global__ __launch_bounds__(256) void scan_block(const int* __restrict__ cnt,
                                                  int* __restrict__ rs,
                                                  int* __restrict__ partials) {
  int t = threadIdx.x;
  int i = blockIdx.x * 256 + t;
  int v = (i < N_NODES) ? ((cnt[i] + 3) & ~3) : 0;   // padded degree
  __shared__ int s[256];
  s[t] = v;
  __syncthreads();
#pragma unroll
  for (int off = 1; off < 256; off <<= 1) {
    int add = (t >= off) ? s[t - off] : 0;
    __syncthreads();
    s[t] += add;
    __syncthreads();
  }
  if (i < N_NODES) rs[i] = s[t] - v;
  if (t == 255) partials[blockIdx.x] = s[255];
}

__global__ __launch_bounds__(256) void scan_partials(int* __restrict__ partials,
                                                     float* __restrict__ red) {
  int t = threadIdx.x;
  if (t == 0) { red[0] = 0.f; red[1] = 0.f; }   // BN partial reset (free ride)
  int v = (t < SCAN_BLOCKS) ? partials[t] : 0;
  __shared__ int s[256];
  s[t] = v;
  __syncthreads();
#pragma unroll
  for (int off = 1; off < 256; off <<= 1) {
    int add = (t >= off) ? s[t - off] : 0;
    __syncthreads();
    s[t] += add;
    __syncthreads();
  }
  if (t < SCAN_BLOCKS) partials[t] = s[t] - v;
}

// add block offsets + write pad slots + zero cnt (cursor) — merged launch.
// Pad bounds derive locally: rs[i+1] = v + padded(cnt[i]).
__global__ __launch_bounds__(256) void add_offsets_pad(
    int* __restrict__ rs, const int* __restrict__ partials,
    int* __restrict__ cnt, int* __restrict__ esrc) {
  int i = blockIdx.x * 256 + threadIdx.x;
  if (i >= N_NODES) return;
  int v = rs[i] + partials[blockIdx.x];
  rs[i] = v;
  int d = cnt[i];
  cnt[i] = 0;
  int pe = v + ((d + 3) & ~3);
  if (i == N_NODES - 1) rs[N_NODES] = pe;
  for (int k = v + d; k < pe; ++k) esrc[k] = N_NODES;
}

// ---------------------------------------------------------------------------
// BN apply: out = (z - mu) * rsqrt(var + eps) * gamma + beta.
// ---------------------------------------------------------------------------
__global__ __launch_bounds__(256) void bn2(const float* __restrict__ z,
                                           const float* __restrict__ red,
                                           const float* __restrict__ gamma,
                                           const float* __restrict__ beta,
                                           float* __restrict__ out) {
  int i = blockIdx.x * 256 + threadIdx.x;
  if (i >= N_NODES) return;
  float mu = red[0] * (1.0f / N_NODES);
  float var = red[1] * (1.0f / N_NODES) - mu * mu;
  out[i] = (z[i] - mu) * rsqrtf(var + BN_EPS) * gamma[0] + beta[0];
}

// ---------------------------------------------------------------------------
extern "C" void kernel_launch(void* const* d_in, const int* in_sizes, int n_in,
                              void* d_out, int out_size, void* d_ws, size_t ws_size,
                              hipStream_t stream) {
  const float* feature = (const float*)d_in[0];
  const int* eidx = (const int*)d_in[1];
  const float* head_W = (const float*)d_in[2];
  const float* head_b = (const float*)d_in[3];
  const float* gin_W1 = (const float*)d_in[4];
  const float* gin_b1 = (const float*)d_in[5];
  const float* lin_W1 = (const float*)d_in[6];
  const float* lin_b1 = (const float*)d_in[7];
  const float* gin_W2 = (const float*)d_in[8];
  const float* gin_b2 = (const float*)d_in[9];
  const float* lin_W2 = (const float*)d_in[10];
  const float* lin_b2 = (const float*)d_in[11];
  const float* tail_W = (const float*)d_in[12];
  const float* tail_b = (const float*)d_in[13];
  const float* bn_gamma = (const float*)d_in[14];
  const float* bn_beta = (const float*)d_in[15];

  float* z = (float*)d_ws;                       // N
  float* red = z + N_NODES;                      // 2 floats
  int* row_start = (int*)(red + 2);              // N+1
  int* cnt = row_start + (N_NODES + 1);          // N
  int* partials = cnt + N_NODES;                 // 256
  int* esrc = (int*)(((uintptr_t)(partials + 256) + 15) & ~(uintptr_t)15);
  // padded CSR: at most E + 3*N = 750000 slots
  unsigned short* wp =
      (unsigned short*)(((uintptr_t)(esrc + 760000) + 15) & ~(uintptr_t)15);
  unsigned short* hH = wp;            // head hi: 512*128
  unsigned short* hL = hH + 65536;    // head lo
  unsigned short* g1H = hL + 65536;   // 128*128 each below
  unsigned short* g1L = g1H + 16384;
  unsigned short* l1H = g1L + 16384;
  unsigned short* l1L = l1H + 16384;
  unsigned short* g2H = l1L + 16384;
  unsigned short* g2L = g2H + 16384;
  unsigned short* l2H = g2L + 16384;
  unsigned short* l2L = l2H + 16384;
  unsigned short* xb0 = l2L + 16384;             // bf16 features A, (N+1) x 128
  unsigned short* xb1 = xb0 + (size_t)(N_NODES + 1) * DH;  // features B (ping-pong)

  const int gin_grid = (N_NODES + 63) / 64;      // 782 (BM=64)
  const int edge_grid = (N_EDGES + 255) / 256;   // 2344

  // ---- zero degree counters ----
  hipMemsetAsync(cnt, 0, N_NODES * sizeof(int), stream);

  // ---- weight pre-split + degree count + both dummy-row zeros: one launch ----
  convert_W5_count<<<512 + edge_grid, 256, 0, stream>>>(
      head_W, gin_W1, lin_W1, gin_W2, lin_W2, hH, hL, g1H, g1L, l1H, l1L,
      g2H, g2L, l2H, l2L, eidx, cnt,
      (unsigned*)(xb0 + (size_t)N_NODES * DH),
      (unsigned*)(xb1 + (size_t)N_NODES * DH));

  // ---- CSR build over padded degrees ----
  scan_block<<<SCAN_BLOCKS, 256, 0, stream>>>(cnt, row_start, partials);
  scan_partials<<<1, 256, 0, stream>>>(partials, red);   // also zeroes red
  add_offsets_pad<<<SCAN_BLOCKS, 256, 0, stream>>>(row_start, partials, cnt, esrc);

  // ---- head GEMM (fused with fill_csr; writes xb0) ----
  gemm_head_fill<<<HEAD_GRID + edge_grid, 256, 0, stream>>>(
      feature, hH, hL, head_b, xb0, N_NODES, eidx, row_start, cnt, esrc);

  // ---- layer 1: fused aggregate + GIN MLP pair (xb0 -> xb1) ----
  gemm_gin_fused<<<gin_grid, 256, 0, stream>>>(
      xb0, row_start, esrc, g1H, g1L, gin_b1, l1H, l1L, lin_b1,
      xb1, N_NODES, nullptr, nullptr, nullptr, nullptr);

  // ---- layer 2: fused aggregate + GIN MLP pair + tail (xb1 -> z, red) ----
  gemm_gin_fused<<<gin_grid, 256, 0, stream>>>(
      xb1, row_start, esrc, g2H, g2L, gin_b2, l2H, l2L, lin_b2,
      nullptr, N_NODES, tail_W, tail_b, z, red);

  // ---- batchnorm apply ----
  bn2<<<(N_NODES + 255) / 256, 256, 0, stream>>>(z, red, bn_gamma, bn_beta, (float*)d_out);
}

// Round 15
// 353.729 us; speedup vs baseline: 1.0084x; 1.0084x over previous
//
#include <hip/hip_runtime.h>

#define N_NODES 50000
#define N_EDGES 600000
#define DH 128
#define BN_EPS 1e-5f
#define SCAN_BLOCKS ((N_NODES + 255) / 256)   // 196
#define HEAD_GRID ((N_NODES + 63) / 64)       // 782

typedef __attribute__((ext_vector_type(8))) short bf16x8;
typedef __attribute__((ext_vector_type(4))) float f32x4;

// round-to-nearest-even fp32 -> bf16 (bit trick, sign-safe)
__device__ inline unsigned short f2bf(float x) {
  unsigned u = __float_as_uint(x);
  return (unsigned short)((u + 0x7FFFu + ((u >> 16) & 1u)) >> 16);
}
__device__ inline float bf2f(unsigned short h) {
  return __uint_as_float(((unsigned)h) << 16);
}

// async global->LDS, 16 B per lane: lane i's data lands at lds_base + i*16.
__device__ inline void gl_lds16(const unsigned short* g, unsigned short* l) {
  __builtin_amdgcn_global_load_lds(
      (const __attribute__((address_space(1))) unsigned int*)g,
      (__attribute__((address_space(3))) unsigned int*)l, 16, 0, 0);
}

// ---------------------------------------------------------------------------
// Fused weight pre-split + edge-degree count (block-range fusion) + dummy-row
// zero for BOTH feature ping-pong buffers (block 0 rides along).
// Column-slot permutation: output col n placed so the epilogue lane's 4
// c-values are CONTIGUOUS output columns (colbase = ch*64 + coln*4 + c):
//   slot ct = (n>>6)*4 + (n&3), slot coln = (n>>2)&15
// k-mapping: plane[((kstep32*8 + ctile)*64 + lane)*8 + j],
// k = kstep32*32 + (lane>>4)*8 + j. W split hi/lo (Wh+Wl == W to 2^-17).
// ---------------------------------------------------------------------------
__global__ __launch_bounds__(256) void convert_W5_count(
    const float* __restrict__ hW, const float* __restrict__ g1,
    const float* __restrict__ l1, const float* __restrict__ g2,
    const float* __restrict__ l2,
    unsigned short* __restrict__ hH, unsigned short* __restrict__ hL,
    unsigned short* __restrict__ g1H, unsigned short* __restrict__ g1L,
    unsigned short* __restrict__ l1H, unsigned short* __restrict__ l1L,
    unsigned short* __restrict__ g2H, unsigned short* __restrict__ g2L,
    unsigned short* __restrict__ l2H, unsigned short* __restrict__ l2L,
    const int* __restrict__ eidx, int* __restrict__ cnt,
    unsigned* __restrict__ dummy0, unsigned* __restrict__ dummy1) {
  int b = blockIdx.x;
  if (b >= 512) {
    int e = (b - 512) * 256 + threadIdx.x;
    if (e < N_EDGES) atomicAdd(&cnt[eidx[N_EDGES + e]], 1);
    return;
  }
  if (b == 0 && threadIdx.x < 64) {
    dummy0[threadIdx.x] = 0u;   // 128 bf16 zeros each
    dummy1[threadIdx.x] = 0u;
  }
  const float* W;
  unsigned short *hi, *lo;
  int idx;
  if (b < 256) {
    W = hW; hi = hH; lo = hL;
    idx = b * 256 + threadIdx.x;
  } else {
    int w = (b - 256) >> 6;
    idx = ((b - 256) & 63) * 256 + threadIdx.x;
    W = (w == 0) ? g1 : (w == 1) ? l1 : (w == 2) ? g2 : l2;
    hi = (w == 0) ? g1H : (w == 1) ? l1H : (w == 2) ? g2H : l2H;
    lo = (w == 0) ? g1L : (w == 1) ? l1L : (w == 2) ? g2L : l2L;
  }
  int k = idx >> 7;
  int n = idx & 127;
  float x = W[idx];
  unsigned short h = f2bf(x);
  unsigned short l = f2bf(x - bf2f(h));
  int kstep = k >> 5;
  int ctile = ((n >> 6) << 2) | (n & 3);
  int cs = (n >> 2) & 15;
  int lane = ((k >> 3) & 3) * 16 + cs;
  int j = k & 7;
  size_t off = ((size_t)(kstep * 8 + ctile) * 64 + lane) * 8 + j;
  hi[off] = h;
  lo[off] = l;
}

// ---------------------------------------------------------------------------
// Head GEMM (K=512) — proven form + fused fill_csr; bf16-only output (fp32 X
// dropped pipeline-wide, R10). BM=64, BK=64, 2 barriers/kstep. LDS ~41 KB.
// ---------------------------------------------------------------------------
__global__ __launch_bounds__(256) void gemm_head_fill(
    const float* __restrict__ A,
    const unsigned short* __restrict__ Bh, const unsigned short* __restrict__ Bl,
    const float* __restrict__ bias,
    unsigned short* __restrict__ xb_out, int M,
    const int* __restrict__ eidx, const int* __restrict__ rs,
    int* __restrict__ cursor, int* __restrict__ esrc) {
  constexpr int K = 512;
  constexpr int KSTEPS = K / 64;
  constexpr int ASTR = 72;  // 64 k + 8 pad (2-way bank alias = free)
  __shared__ __align__(16) unsigned short Ah[64 * ASTR];   // 9.2 KB
  __shared__ __align__(16) unsigned short Bhs[2][4096];    // 16 KB
  __shared__ __align__(16) unsigned short Bls[2][4096];    // 16 KB

  if (blockIdx.x >= HEAD_GRID) {
    // ---- fill_csr part: scatter edge sources into CSR slots ----
    int e = (blockIdx.x - HEAD_GRID) * 256 + threadIdx.x;
    if (e < N_EDGES) {
      int d = eidx[N_EDGES + e];
      int p = atomicAdd(&cursor[d], 1);
      esrc[rs[d] + p] = eidx[e];
    }
    return;
  }

  const int tid = threadIdx.x;
  const int wave = tid >> 6;
  const int lane = tid & 63;
  const int m0 = blockIdx.x * 64;

  // A staging: thread owns row tid>>2 (0..63), 16-elem group tid&3
  const int s_row = tid >> 2;
  const int s_grp = tid & 3;
  const int g_row = m0 + s_row;
  const int g_rowc = (g_row < M) ? g_row : (M - 1);
  const float* af = A + (size_t)g_rowc * K + s_grp * 16;

  const int rgrp = wave & 1;  // 32-row group
  const int ch = wave >> 1;   // 64-col half

  f32x4 acc[2][4];
#pragma unroll
  for (int r = 0; r < 2; ++r)
#pragma unroll
    for (int c = 0; c < 4; ++c) acc[r][c] = (f32x4){0.f, 0.f, 0.f, 0.f};

  for (int ks = 0; ks < KSTEPS; ++ks) {
    // ---- stage A (64 rows x 64 k fp32 -> bf16) ----
    {
      float4 f0 = *(const float4*)(af + ks * 64);
      float4 f1 = *(const float4*)(af + ks * 64 + 4);
      float4 f2 = *(const float4*)(af + ks * 64 + 8);
      float4 f3 = *(const float4*)(af + ks * 64 + 12);
      ushort4 h0, h1, h2, h3;
      h0.x = f2bf(f0.x); h0.y = f2bf(f0.y); h0.z = f2bf(f0.z); h0.w = f2bf(f0.w);
      h1.x = f2bf(f1.x); h1.y = f2bf(f1.y); h1.z = f2bf(f1.z); h1.w = f2bf(f1.w);
      h2.x = f2bf(f2.x); h2.y = f2bf(f2.y); h2.z = f2bf(f2.z); h2.w = f2bf(f2.w);
      h3.x = f2bf(f3.x); h3.y = f2bf(f3.y); h3.z = f2bf(f3.z); h3.w = f2bf(f3.w);
      int base = s_row * ASTR + s_grp * 16;
      *(ushort4*)&Ah[base + 0] = h0;
      *(ushort4*)&Ah[base + 4] = h1;
      *(ushort4*)&Ah[base + 8] = h2;
      *(ushort4*)&Ah[base + 12] = h3;
    }
    // ---- stage B: two 32-k sub-steps, 8 KB per plane each ----
#pragma unroll
    for (int s = 0; s < 2; ++s) {
      const unsigned short* sh = Bh + (size_t)(2 * ks + s) * 4096 + wave * 1024;
      const unsigned short* sl = Bl + (size_t)(2 * ks + s) * 4096 + wave * 1024;
      gl_lds16(sh + lane * 8, &Bhs[s][wave * 1024]);
      gl_lds16(sh + 512 + lane * 8, &Bhs[s][wave * 1024 + 512]);
      gl_lds16(sl + lane * 8, &Bls[s][wave * 1024]);
      gl_lds16(sl + 512 + lane * 8, &Bls[s][wave * 1024 + 512]);
    }
    __syncthreads();

    // ---- compute: 2 k-chunks x 4 c-tiles x (hi+lo) x 2 row-frags ----
#pragma unroll
    for (int s = 0; s < 2; ++s) {
      bf16x8 a0 = *(const bf16x8*)&Ah[(rgrp * 32 + (lane & 15)) * ASTR + s * 32 + (lane >> 4) * 8];
      bf16x8 a1 = *(const bf16x8*)&Ah[(rgrp * 32 + 16 + (lane & 15)) * ASTR + s * 32 + (lane >> 4) * 8];
#pragma unroll
      for (int c = 0; c < 4; ++c) {
        int ct = ch * 4 + c;
        bf16x8 bh = *(const bf16x8*)&Bhs[s][(ct * 64 + lane) * 8];
        bf16x8 bl = *(const bf16x8*)&Bls[s][(ct * 64 + lane) * 8];
        acc[0][c] = __builtin_amdgcn_mfma_f32_16x16x32_bf16(a0, bh, acc[0][c], 0, 0, 0);
        acc[0][c] = __builtin_amdgcn_mfma_f32_16x16x32_bf16(a0, bl, acc[0][c], 0, 0, 0);
        acc[1][c] = __builtin_amdgcn_mfma_f32_16x16x32_bf16(a1, bh, acc[1][c], 0, 0, 0);
        acc[1][c] = __builtin_amdgcn_mfma_f32_16x16x32_bf16(a1, bl, acc[1][c], 0, 0, 0);
      }
    }
    __syncthreads();
  }

  // ---- epilogue: bf16 mirror only (slot c = output col colbase+c) ----
  const int coln = lane & 15;
  const int rown = (lane >> 4) * 4;
  const int colbase = ch * 64 + coln * 4;
  const float4 bv = *(const float4*)(bias + colbase);
#pragma unroll
  for (int r = 0; r < 2; ++r) {
#pragma unroll
    for (int reg = 0; reg < 4; ++reg) {
      int row = m0 + rgrp * 32 + r * 16 + rown + reg;
      if (row < M) {
        ushort4 hb;
        hb.x = f2bf(fmaxf(acc[r][0][reg] + bv.x, 0.f));
        hb.y = f2bf(fmaxf(acc[r][1][reg] + bv.y, 0.f));
        hb.z = f2bf(fmaxf(acc[r][2][reg] + bv.z, 0.f));
        hb.w = f2bf(fmaxf(acc[r][3][reg] + bv.w, 0.f));
        *(ushort4*)&xb_out[(size_t)row * DH + colbase] = hb;
      }
    }
  }
}

// ---------------------------------------------------------------------------
// FUSED aggregate + GIN MLP pair (R11 proven gather form — R14's 4-thr/node
// variant was neutral-to-worse, so reverted). Each wave aggregates 16 of the
// block's 64 nodes directly into Hb (lane owns dims 2l, 2l+1); stage 1 reads
// A-fragments straight from Hb; stage 2 overwrites Hb with h
// (barrier-ordered). B1(0) prefetched before the gather.
// Epilogue: layer 1 -> xb_out bf16; layer 2 -> fused tail (z + BN partials).
// LDS: 8 + 8 + 17.4 = 33.4 KB -> 4 blocks/CU.
// ---------------------------------------------------------------------------
__global__ __launch_bounds__(256) void gemm_gin_fused(
    const unsigned short* __restrict__ xb_in,
    const int* __restrict__ rs, const int* __restrict__ esrc,
    const unsigned short* __restrict__ B1h, const unsigned short* __restrict__ B1l,
    const float* __restrict__ b1,
    const unsigned short* __restrict__ B2h, const unsigned short* __restrict__ B2l,
    const float* __restrict__ b2,
    unsigned short* __restrict__ xb_out, int M,
    const float* __restrict__ tw, const float* __restrict__ tb,
    float* __restrict__ z, float* __restrict__ red) {
  constexpr int KSTEPS = 4;   // K=128, BK=32
  constexpr int HSTR = 136;   // 128 + 8 pad
  __shared__ __align__(16) unsigned short Bhs[4096];       // 8 KB
  __shared__ __align__(16) unsigned short Bls[4096];       // 8 KB
  __shared__ __align__(16) unsigned short Hb[64 * HSTR];   // 17.4 KB (y, then h)

  const int tid = threadIdx.x;
  const int wave = tid >> 6;
  const int lane = tid & 63;
  const int m0 = blockIdx.x * 64;

  const int rgrp = wave & 1;
  const int ch = wave >> 1;
  const int coln = lane & 15;
  const int rown = (lane >> 4) * 4;
  const int colbase = ch * 64 + coln * 4;

  auto issueB = [&](const unsigned short* Bh, const unsigned short* Bl, int ks) {
    const unsigned short* sh = Bh + (size_t)ks * 4096 + wave * 1024;
    const unsigned short* sl = Bl + (size_t)ks * 4096 + wave * 1024;
    gl_lds16(sh + lane * 8, &Bhs[wave * 1024]);
    gl_lds16(sh + 512 + lane * 8, &Bhs[wave * 1024 + 512]);
    gl_lds16(sl + lane * 8, &Bls[wave * 1024]);
    gl_lds16(sl + 512 + lane * 8, &Bls[wave * 1024 + 512]);
  };

  // ---- B1(0) in flight before the gather phase ----
  issueB(B1h, B1l, 0);

  // ================= aggregation phase: y -> Hb (bf16) =================
  // Wave w aggregates local rows w*16..w*16+15; lane owns dims (2l, 2l+1).
  {
    const unsigned* xb2 = (const unsigned*)xb_in;  // 2 bf16 per uint
    for (int i = 0; i < 16; ++i) {
      int lrow = wave * 16 + i;
      int node = m0 + lrow;
      float2 acc2 = {0.f, 0.f};
      if (node < M) {
        unsigned vs = xb2[(size_t)node * 64 + lane];
        acc2.x = __uint_as_float(vs << 16);
        acc2.y = __uint_as_float(vs & 0xFFFF0000u);
        int j = rs[node];
        int end = rs[node + 1];
        for (; j + 8 <= end; j += 8) {
          int4 ia = *(const int4*)&esrc[j];
          int4 ib = *(const int4*)&esrc[j + 4];
          unsigned v0 = xb2[(size_t)ia.x * 64 + lane];
          unsigned v1 = xb2[(size_t)ia.y * 64 + lane];
          unsigned v2 = xb2[(size_t)ia.z * 64 + lane];
          unsigned v3 = xb2[(size_t)ia.w * 64 + lane];
          unsigned v4 = xb2[(size_t)ib.x * 64 + lane];
          unsigned v5 = xb2[(size_t)ib.y * 64 + lane];
          unsigned v6 = xb2[(size_t)ib.z * 64 + lane];
          unsigned v7 = xb2[(size_t)ib.w * 64 + lane];
          acc2.x += ((__uint_as_float(v0 << 16) + __uint_as_float(v1 << 16)) +
                     (__uint_as_float(v2 << 16) + __uint_as_float(v3 << 16))) +
                    ((__uint_as_float(v4 << 16) + __uint_as_float(v5 << 16)) +
                     (__uint_as_float(v6 << 16) + __uint_as_float(v7 << 16)));
          acc2.y += ((__uint_as_float(v0 & 0xFFFF0000u) + __uint_as_float(v1 & 0xFFFF0000u)) +
                     (__uint_as_float(v2 & 0xFFFF0000u) + __uint_as_float(v3 & 0xFFFF0000u))) +
                    ((__uint_as_float(v4 & 0xFFFF0000u) + __uint_as_float(v5 & 0xFFFF0000u)) +
                     (__uint_as_float(v6 & 0xFFFF0000u) + __uint_as_float(v7 & 0xFFFF0000u)));
        }
        if (j < end) {  // exactly one aligned 4-batch remains
          int4 ia = *(const int4*)&esrc[j];
          unsigned v0 = xb2[(size_t)ia.x * 64 + lane];
          unsigned v1 = xb2[(size_t)ia.y * 64 + lane];
          unsigned v2 = xb2[(size_t)ia.z * 64 + lane];
          unsigned v3 = xb2[(size_t)ia.w * 64 + lane];
          acc2.x += (__uint_as_float(v0 << 16) + __uint_as_float(v1 << 16)) +
                    (__uint_as_float(v2 << 16) + __uint_as_float(v3 << 16));
          acc2.y += (__uint_as_float(v0 & 0xFFFF0000u) + __uint_as_float(v1 & 0xFFFF0000u)) +
                    (__uint_as_float(v2 & 0xFFFF0000u) + __uint_as_float(v3 & 0xFFFF0000u));
        }
      }
      // lane l owns dims 2l,2l+1 -> 4-B aligned LDS write, 2-way bank alias
      *(unsigned*)&Hb[lrow * HSTR + 2 * lane] =
          (unsigned)f2bf(acc2.x) | ((unsigned)f2bf(acc2.y) << 16);
    }
  }

  f32x4 acc[2][4];
#pragma unroll
  for (int r = 0; r < 2; ++r)
#pragma unroll
    for (int c = 0; c < 4; ++c) acc[r][c] = (f32x4){0.f, 0.f, 0.f, 0.f};

  // ================= stage 1: h = relu(y @ W1 + b1) =================
  for (int ks = 0; ks < KSTEPS; ++ks) {
    if (ks > 0) issueB(B1h, B1l, ks);
    __syncthreads();  // iter 0: publishes Hb (y) + B1(0)
    bf16x8 a0 = *(const bf16x8*)&Hb[(rgrp * 32 + (lane & 15)) * HSTR + ks * 32 + (lane >> 4) * 8];
    bf16x8 a1 = *(const bf16x8*)&Hb[(rgrp * 32 + 16 + (lane & 15)) * HSTR + ks * 32 + (lane >> 4) * 8];
#pragma unroll
    for (int c = 0; c < 4; ++c) {
      int ct = ch * 4 + c;
      bf16x8 bh = *(const bf16x8*)&Bhs[(ct * 64 + lane) * 8];
      bf16x8 bl = *(const bf16x8*)&Bls[(ct * 64 + lane) * 8];
      acc[0][c] = __builtin_amdgcn_mfma_f32_16x16x32_bf16(a0, bh, acc[0][c], 0, 0, 0);
      acc[0][c] = __builtin_amdgcn_mfma_f32_16x16x32_bf16(a0, bl, acc[0][c], 0, 0, 0);
      acc[1][c] = __builtin_amdgcn_mfma_f32_16x16x32_bf16(a1, bh, acc[1][c], 0, 0, 0);
      acc[1][c] = __builtin_amdgcn_mfma_f32_16x16x32_bf16(a1, bl, acc[1][c], 0, 0, 0);
    }
    __syncthreads();
  }

  // ---- h -> Hb (overwrites y; all stage-1 reads completed at last barrier) ----
  {
    const float4 bv = *(const float4*)(b1 + colbase);
#pragma unroll
    for (int r = 0; r < 2; ++r) {
#pragma unroll
      for (int reg = 0; reg < 4; ++reg) {
        int lrow = rgrp * 32 + r * 16 + rown + reg;
        ushort4 hb;
        hb.x = f2bf(fmaxf(acc[r][0][reg] + bv.x, 0.f));
        hb.y = f2bf(fmaxf(acc[r][1][reg] + bv.y, 0.f));
        hb.z = f2bf(fmaxf(acc[r][2][reg] + bv.z, 0.f));
        hb.w = f2bf(fmaxf(acc[r][3][reg] + bv.w, 0.f));
        *(ushort4*)&Hb[lrow * HSTR + colbase] = hb;
      }
    }
#pragma unroll
    for (int r = 0; r < 2; ++r)
#pragma unroll
      for (int c = 0; c < 4; ++c) acc[r][c] = (f32x4){0.f, 0.f, 0.f, 0.f};
  }

  // ================= stage 2: out = h @ W2 + b2 =================
  for (int ks = 0; ks < KSTEPS; ++ks) {
    issueB(B2h, B2l, ks);
    __syncthreads();  // first iter: also publishes h to all waves
    bf16x8 a0 = *(const bf16x8*)&Hb[(rgrp * 32 + (lane & 15)) * HSTR + ks * 32 + (lane >> 4) * 8];
    bf16x8 a1 = *(const bf16x8*)&Hb[(rgrp * 32 + 16 + (lane & 15)) * HSTR + ks * 32 + (lane >> 4) * 8];
#pragma unroll
    for (int c = 0; c < 4; ++c) {
      int ct = ch * 4 + c;
      bf16x8 bh = *(const bf16x8*)&Bhs[(ct * 64 + lane) * 8];
      bf16x8 bl = *(const bf16x8*)&Bls[(ct * 64 + lane) * 8];
      acc[0][c] = __builtin_amdgcn_mfma_f32_16x16x32_bf16(a0, bh, acc[0][c], 0, 0, 0);
      acc[0][c] = __builtin_amdgcn_mfma_f32_16x16x32_bf16(a0, bl, acc[0][c], 0, 0, 0);
      acc[1][c] = __builtin_amdgcn_mfma_f32_16x16x32_bf16(a1, bh, acc[1][c], 0, 0, 0);
      acc[1][c] = __builtin_amdgcn_mfma_f32_16x16x32_bf16(a1, bl, acc[1][c], 0, 0, 0);
    }
    __syncthreads();  // last iter: Hb reads complete -> safe to reuse below
  }

  const float4 bv = *(const float4*)(b2 + colbase);

  if (tw == nullptr) {
    // ---- layer-1 epilogue: bf16 features only ----
#pragma unroll
    for (int r = 0; r < 2; ++r) {
#pragma unroll
      for (int reg = 0; reg < 4; ++reg) {
        int row = m0 + rgrp * 32 + r * 16 + rown + reg;
        if (row < M) {
          ushort4 hb;
          hb.x = f2bf(acc[r][0][reg] + bv.x);
          hb.y = f2bf(acc[r][1][reg] + bv.y);
          hb.z = f2bf(acc[r][2][reg] + bv.z);
          hb.w = f2bf(acc[r][3][reg] + bv.w);
          *(ushort4*)&xb_out[(size_t)row * DH + colbase] = hb;
        }
      }
    }
  } else {
    // ---- layer-2 fused-tail epilogue: z + BN partials, no feature write ----
    float* zpart = (float*)Hb;  // 64 x 33 fp32 = 8.4 KB (fits in 17.4 KB)
    const float4 tw4 = *(const float4*)(tw + colbase);
#pragma unroll
    for (int r = 0; r < 2; ++r) {
#pragma unroll
      for (int reg = 0; reg < 4; ++reg) {
        int lrow = rgrp * 32 + r * 16 + rown + reg;
        float4 v;
        v.x = acc[r][0][reg] + bv.x;
        v.y = acc[r][1][reg] + bv.y;
        v.z = acc[r][2][reg] + bv.z;
        v.w = acc[r][3][reg] + bv.w;
        zpart[lrow * 33 + ch * 16 + coln] =
            v.x * tw4.x + v.y * tw4.y + v.z * tw4.z + v.w * tw4.w;
      }
    }
    __syncthreads();
    if (tid < 64) {
      int row = m0 + tid;
      float s = 0.f;
#pragma unroll
      for (int k = 0; k < 32; ++k) s += zpart[tid * 33 + k];
      float zv = s + tb[0];
      bool valid = row < M;
      if (valid) z[row] = zv;
      float a = valid ? zv : 0.f;
      float q = valid ? zv * zv : 0.f;
#pragma unroll
      for (int m = 32; m; m >>= 1) {
        a += __shfl_xor(a, m);
        q += __shfl_xor(q, m);
      }
      if (tid == 0) {
        atomicAdd(&red[0], a);
        atomicAdd(&red[1], q);
      }
    }
  }
}

// ---------------------------------------------------------------------------
// CSR build: exclusive scan over PADDED degrees (pad to multiple of 4 so the
// gather's index loads are aligned int4 and the edge loop has no tails).
// Pad slots point at dummy node N_NODES whose feature rows are zeroed.
// R15: scan_partials launch DELETED — add_offsets_pad computes its own block
// prefix from the raw per-block sums (196 ints, one LDS reduce).
// ---------------------------------------------------------------------------
__global__ __launch_bounds__(256) void scan_block(const int* __restrict__ cnt,
                                                  int* __restrict__ rs,
                                                  int* __restrict__ partials,
                                                  float* __restrict__ red) {
  int t = threadIdx.x;
  if (blockIdx.x == 0 && t == 0) { red[0] = 0.f; red[1] = 0.f; }
  int i = blockIdx.x * 256 + t;
  int v = (i < N_NODES) ? ((cnt[i] + 3) & ~3) : 0;   // padded degree
  __shared__ int s[256];
  s[t] = v;
  __syncthreads();
#pragma unroll
  for (int off = 1; off < 256; off <<= 1) {
    int add = (t >= off) ? s[t - off] : 0;
    __syncthreads();
    s[t] += add;
    __syncthreads();
  }
  if (i < N_NODES) rs[i] = s[t] - v;
  if (t == 255) partials[blockIdx.x] = s[255];
}

// add block offsets (self-computed prefix of raw partials) + write pad slots
// + zero cnt (cursor) — merged. Pad bounds derive locally.
__global__ __launch_bounds__(256) void add_offsets_pad(
    int* __restrict__ rs, const int* __restrict__ partials,
    int* __restrict__ cnt, int* __restrict__ esrc) {
  __shared__ int s[256];
  int t = threadIdx.x;
  s[t] = (t < (int)blockIdx.x) ? partials[t] : 0;   // blockIdx.x <= 195 < 256
  __syncthreads();
  for (int off = 128; off; off >>= 1) {
    if (t < off) s[t] += s[t + off];
    __syncthreads();
  }
  int base = s[0];
  int i = blockIdx.x * 256 + t;
  if (i >= N_NODES) return;
  int v = rs[i] + base;
  rs[i] = v;
  int d = cnt[i];
  cnt[i] = 0;
  int pe = v + ((d + 3) & ~3);
  if (i == N_NODES - 1) rs[N_NODES] = pe;
  for (int k = v + d; k < pe; ++k) esrc[k] = N_NODES;
}

// ---------------------------------------------------------------------------
// BN apply: out = (z - mu) * rsqrt(var + eps) * gamma + beta.
// ---------------------------------------------------------------------------
__global__ __launch_bounds__(256) void bn2(const float* __restrict__ z,
                                           const float* __restrict__ red,
                                           const float* __restrict__ gamma,
                                           const float* __restrict__ beta,
                                           float* __restrict__ out) {
  int i = blockIdx.x * 256 + threadIdx.x;
  if (i >= N_NODES) return;
  float mu = red[0] * (1.0f / N_NODES);
  float var = red[1] * (1.0f / N_NODES) - mu * mu;
  out[i] = (z[i] - mu) * rsqrtf(var + BN_EPS) * gamma[0] + beta[0];
}

// ---------------------------------------------------------------------------
extern "C" void kernel_launch(void* const* d_in, const int* in_sizes, int n_in,
                              void* d_out, int out_size, void* d_ws, size_t ws_size,
                              hipStream_t stream) {
  const float* feature = (const float*)d_in[0];
  const int* eidx = (const int*)d_in[1];
  const float* head_W = (const float*)d_in[2];
  const float* head_b = (const float*)d_in[3];
  const float* gin_W1 = (const float*)d_in[4];
  const float* gin_b1 = (const float*)d_in[5];
  const float* lin_W1 = (const float*)d_in[6];
  const float* lin_b1 = (const float*)d_in[7];
  const float* gin_W2 = (const float*)d_in[8];
  const float* gin_b2 = (const float*)d_in[9];
  const float* lin_W2 = (const float*)d_in[10];
  const float* lin_b2 = (const float*)d_in[11];
  const float* tail_W = (const float*)d_in[12];
  const float* tail_b = (const float*)d_in[13];
  const float* bn_gamma = (const float*)d_in[14];
  const float* bn_beta = (const float*)d_in[15];

  float* z = (float*)d_ws;                       // N
  float* red = z + N_NODES;                      // 2 floats
  int* row_start = (int*)(red + 2);              // N+1
  int* cnt = row_start + (N_NODES + 1);          // N
  int* partials = cnt + N_NODES;                 // 256
  int* esrc = (int*)(((uintptr_t)(partials + 256) + 15) & ~(uintptr_t)15);
  // padded CSR: at most E + 3*N = 750000 slots
  unsigned short* wp =
      (unsigned short*)(((uintptr_t)(esrc + 760000) + 15) & ~(uintptr_t)15);
  unsigned short* hH = wp;            // head hi: 512*128
  unsigned short* hL = hH + 65536;    // head lo
  unsigned short* g1H = hL + 65536;   // 128*128 each below
  unsigned short* g1L = g1H + 16384;
  unsigned short* l1H = g1L + 16384;
  unsigned short* l1L = l1H + 16384;
  unsigned short* g2H = l1L + 16384;
  unsigned short* g2L = g2H + 16384;
  unsigned short* l2H = g2L + 16384;
  unsigned short* l2L = l2H + 16384;
  unsigned short* xb0 = l2L + 16384;             // bf16 features A, (N+1) x 128
  unsigned short* xb1 = xb0 + (size_t)(N_NODES + 1) * DH;  // features B (ping-pong)

  const int gin_grid = (N_NODES + 63) / 64;      // 782 (BM=64)
  const int edge_grid = (N_EDGES + 255) / 256;   // 2344

  // ---- zero degree counters ----
  hipMemsetAsync(cnt, 0, N_NODES * sizeof(int), stream);

  // ---- weight pre-split + degree count + both dummy-row zeros: one launch ----
  convert_W5_count<<<512 + edge_grid, 256, 0, stream>>>(
      head_W, gin_W1, lin_W1, gin_W2, lin_W2, hH, hL, g1H, g1L, l1H, l1L,
      g2H, g2L, l2H, l2L, eidx, cnt,
      (unsigned*)(xb0 + (size_t)N_NODES * DH),
      (unsigned*)(xb1 + (size_t)N_NODES * DH));

  // ---- CSR build over padded degrees (2 launches; prefix fused into 2nd) ----
  scan_block<<<SCAN_BLOCKS, 256, 0, stream>>>(cnt, row_start, partials, red);
  add_offsets_pad<<<SCAN_BLOCKS, 256, 0, stream>>>(row_start, partials, cnt, esrc);

  // ---- head GEMM (fused with fill_csr; writes xb0) ----
  gemm_head_fill<<<HEAD_GRID + edge_grid, 256, 0, stream>>>(
      feature, hH, hL, head_b, xb0, N_NODES, eidx, row_start, cnt, esrc);

  // ---- layer 1: fused aggregate + GIN MLP pair (xb0 -> xb1) ----
  gemm_gin_fused<<<gin_grid, 256, 0, stream>>>(
      xb0, row_start, esrc, g1H, g1L, gin_b1, l1H, l1L, lin_b1,
      xb1, N_NODES, nullptr, nullptr, nullptr, nullptr);

  // ---- layer 2: fused aggregate + GIN MLP pair + tail (xb1 -> z, red) ----
  gemm_gin_fused<<<gin_grid, 256, 0, stream>>>(
      xb1, row_start, esrc, g2H, g2L, gin_b2, l2H, l2L, lin_b2,
      nullptr, N_NODES, tail_W, tail_b, z, red);

  // ---- batchnorm apply ----
  bn2<<<(N_NODES + 255) / 256, 256, 0, stream>>>(z, red, bn_gamma, bn_beta, (float*)d_out);
}

// Round 16
// 349.253 us; speedup vs baseline: 1.0213x; 1.0128x over previous
//
#include <hip/hip_runtime.h>

#define N_NODES 50000
#define N_EDGES 600000
#define DH 128
#define BN_EPS 1e-5f
#define SCAN_BLOCKS ((N_NODES + 255) / 256)   // 196
#define HEAD_GRID ((N_NODES + 63) / 64)       // 782

typedef __attribute__((ext_vector_type(8))) short bf16x8;
typedef __attribute__((ext_vector_type(4))) float f32x4;

// round-to-nearest-even fp32 -> bf16 (bit trick, sign-safe)
__device__ inline unsigned short f2bf(float x) {
  unsigned u = __float_as_uint(x);
  return (unsigned short)((u + 0x7FFFu + ((u >> 16) & 1u)) >> 16);
}
__device__ inline float bf2f(unsigned short h) {
  return __uint_as_float(((unsigned)h) << 16);
}

// ---------------------------------------------------------------------------
// Fused weight pre-split + edge-degree count (block-range fusion) + dummy-row
// zero for BOTH feature ping-pong buffers (block 0 rides along).
// Column-slot permutation: output col n placed so the epilogue lane's 4
// c-values are CONTIGUOUS output columns (colbase = ch*64 + coln*4 + c):
//   slot ct = (n>>6)*4 + (n&3), slot coln = (n>>2)&15
// k-mapping: plane[((kstep32*8 + ctile)*64 + lane)*8 + j],
// k = kstep32*32 + (lane>>4)*8 + j. W split hi/lo (Wh+Wl == W to 2^-17).
// ---------------------------------------------------------------------------
__global__ __launch_bounds__(256) void convert_W5_count(
    const float* __restrict__ hW, const float* __restrict__ g1,
    const float* __restrict__ l1, const float* __restrict__ g2,
    const float* __restrict__ l2,
    unsigned short* __restrict__ hH, unsigned short* __restrict__ hL,
    unsigned short* __restrict__ g1H, unsigned short* __restrict__ g1L,
    unsigned short* __restrict__ l1H, unsigned short* __restrict__ l1L,
    unsigned short* __restrict__ g2H, unsigned short* __restrict__ g2L,
    unsigned short* __restrict__ l2H, unsigned short* __restrict__ l2L,
    const int* __restrict__ eidx, int* __restrict__ cnt,
    unsigned* __restrict__ dummy0, unsigned* __restrict__ dummy1) {
  int b = blockIdx.x;
  if (b >= 512) {
    int e = (b - 512) * 256 + threadIdx.x;
    if (e < N_EDGES) atomicAdd(&cnt[eidx[N_EDGES + e]], 1);
    return;
  }
  if (b == 0 && threadIdx.x < 64) {
    dummy0[threadIdx.x] = 0u;   // 128 bf16 zeros each
    dummy1[threadIdx.x] = 0u;
  }
  const float* W;
  unsigned short *hi, *lo;
  int idx;
  if (b < 256) {
    W = hW; hi = hH; lo = hL;
    idx = b * 256 + threadIdx.x;
  } else {
    int w = (b - 256) >> 6;
    idx = ((b - 256) & 63) * 256 + threadIdx.x;
    W = (w == 0) ? g1 : (w == 1) ? l1 : (w == 2) ? g2 : l2;
    hi = (w == 0) ? g1H : (w == 1) ? l1H : (w == 2) ? g2H : l2H;
    lo = (w == 0) ? g1L : (w == 1) ? l1L : (w == 2) ? g2L : l2L;
  }
  int k = idx >> 7;
  int n = idx & 127;
  float x = W[idx];
  unsigned short h = f2bf(x);
  unsigned short l = f2bf(x - bf2f(h));
  int kstep = k >> 5;
  int ctile = ((n >> 6) << 2) | (n & 3);
  int cs = (n >> 2) & 15;
  int lane = ((k >> 3) & 3) * 16 + cs;
  int j = k & 7;
  size_t off = ((size_t)(kstep * 8 + ctile) * 64 + lane) * 8 + j;
  hi[off] = h;
  lo[off] = l;
}

// ---------------------------------------------------------------------------
// Head GEMM (K=512) — R16: B staged via ordinary uint4 loads -> registers ->
// ds_write_b128 (global_load_lds REMOVED). Rationale: every head variant
// R0-R15 kept 8 gl_lds16/thread/kstep and all hit the same ~70 us floor
// regardless of occupancy/schedule/tile; the direct-to-LDS DMA path is the
// one untested invariant (suspected serialized per-CU resource drained at
// each barrier). LDS contents byte-identical -> numerics unchanged.
// BM=64, BK=64, 2 barriers/kstep, fused fill_csr, bf16-only output.
// ---------------------------------------------------------------------------
__global__ __launch_bounds__(256) void gemm_head_fill(
    const float* __restrict__ A,
    const unsigned short* __restrict__ Bh, const unsigned short* __restrict__ Bl,
    const float* __restrict__ bias,
    unsigned short* __restrict__ xb_out, int M,
    const int* __restrict__ eidx, const int* __restrict__ rs,
    int* __restrict__ cursor, int* __restrict__ esrc) {
  constexpr int K = 512;
  constexpr int KSTEPS = K / 64;
  constexpr int ASTR = 72;  // 64 k + 8 pad (2-way bank alias = free)
  __shared__ __align__(16) unsigned short Ah[64 * ASTR];   // 9.2 KB
  __shared__ __align__(16) unsigned short Bhs[2][4096];    // 16 KB
  __shared__ __align__(16) unsigned short Bls[2][4096];    // 16 KB

  if (blockIdx.x >= HEAD_GRID) {
    // ---- fill_csr part: scatter edge sources into CSR slots ----
    int e = (blockIdx.x - HEAD_GRID) * 256 + threadIdx.x;
    if (e < N_EDGES) {
      int d = eidx[N_EDGES + e];
      int p = atomicAdd(&cursor[d], 1);
      esrc[rs[d] + p] = eidx[e];
    }
    return;
  }

  const int tid = threadIdx.x;
  const int wave = tid >> 6;
  const int lane = tid & 63;
  const int m0 = blockIdx.x * 64;

  // A staging: thread owns row tid>>2 (0..63), 16-elem group tid&3
  const int s_row = tid >> 2;
  const int s_grp = tid & 3;
  const int g_row = m0 + s_row;
  const int g_rowc = (g_row < M) ? g_row : (M - 1);
  const float* af = A + (size_t)g_rowc * K + s_grp * 16;

  const int rgrp = wave & 1;  // 32-row group
  const int ch = wave >> 1;   // 64-col half

  f32x4 acc[2][4];
#pragma unroll
  for (int r = 0; r < 2; ++r)
#pragma unroll
    for (int c = 0; c < 4; ++c) acc[r][c] = (f32x4){0.f, 0.f, 0.f, 0.f};

  for (int ks = 0; ks < KSTEPS; ++ks) {
    // ---- stage B: issue all 8 global uint4 loads FIRST (max MLP) ----
    const unsigned short* sh0 = Bh + (size_t)(2 * ks + 0) * 4096 + wave * 1024;
    const unsigned short* sl0 = Bl + (size_t)(2 * ks + 0) * 4096 + wave * 1024;
    const unsigned short* sh1 = Bh + (size_t)(2 * ks + 1) * 4096 + wave * 1024;
    const unsigned short* sl1 = Bl + (size_t)(2 * ks + 1) * 4096 + wave * 1024;
    uint4 bh00 = *(const uint4*)(sh0 + lane * 8);
    uint4 bh01 = *(const uint4*)(sh0 + 512 + lane * 8);
    uint4 bl00 = *(const uint4*)(sl0 + lane * 8);
    uint4 bl01 = *(const uint4*)(sl0 + 512 + lane * 8);
    uint4 bh10 = *(const uint4*)(sh1 + lane * 8);
    uint4 bh11 = *(const uint4*)(sh1 + 512 + lane * 8);
    uint4 bl10 = *(const uint4*)(sl1 + lane * 8);
    uint4 bl11 = *(const uint4*)(sl1 + 512 + lane * 8);

    // ---- stage A (64 rows x 64 k fp32 -> bf16) ----
    {
      float4 f0 = *(const float4*)(af + ks * 64);
      float4 f1 = *(const float4*)(af + ks * 64 + 4);
      float4 f2 = *(const float4*)(af + ks * 64 + 8);
      float4 f3 = *(const float4*)(af + ks * 64 + 12);
      ushort4 h0, h1, h2, h3;
      h0.x = f2bf(f0.x); h0.y = f2bf(f0.y); h0.z = f2bf(f0.z); h0.w = f2bf(f0.w);
      h1.x = f2bf(f1.x); h1.y = f2bf(f1.y); h1.z = f2bf(f1.z); h1.w = f2bf(f1.w);
      h2.x = f2bf(f2.x); h2.y = f2bf(f2.y); h2.z = f2bf(f2.z); h2.w = f2bf(f2.w);
      h3.x = f2bf(f3.x); h3.y = f2bf(f3.y); h3.z = f2bf(f3.z); h3.w = f2bf(f3.w);
      int base = s_row * ASTR + s_grp * 16;
      *(ushort4*)&Ah[base + 0] = h0;
      *(ushort4*)&Ah[base + 4] = h1;
      *(ushort4*)&Ah[base + 8] = h2;
      *(ushort4*)&Ah[base + 12] = h3;
    }
    // ---- B -> LDS (same layout gl_lds16 produced: lane i at base+i*16B) ----
    *(uint4*)&Bhs[0][wave * 1024 + lane * 8] = bh00;
    *(uint4*)&Bhs[0][wave * 1024 + 512 + lane * 8] = bh01;
    *(uint4*)&Bls[0][wave * 1024 + lane * 8] = bl00;
    *(uint4*)&Bls[0][wave * 1024 + 512 + lane * 8] = bl01;
    *(uint4*)&Bhs[1][wave * 1024 + lane * 8] = bh10;
    *(uint4*)&Bhs[1][wave * 1024 + 512 + lane * 8] = bh11;
    *(uint4*)&Bls[1][wave * 1024 + lane * 8] = bl10;
    *(uint4*)&Bls[1][wave * 1024 + 512 + lane * 8] = bl11;
    __syncthreads();

    // ---- compute: 2 k-chunks x 4 c-tiles x (hi+lo) x 2 row-frags ----
#pragma unroll
    for (int s = 0; s < 2; ++s) {
      bf16x8 a0 = *(const bf16x8*)&Ah[(rgrp * 32 + (lane & 15)) * ASTR + s * 32 + (lane >> 4) * 8];
      bf16x8 a1 = *(const bf16x8*)&Ah[(rgrp * 32 + 16 + (lane & 15)) * ASTR + s * 32 + (lane >> 4) * 8];
#pragma unroll
      for (int c = 0; c < 4; ++c) {
        int ct = ch * 4 + c;
        bf16x8 bh = *(const bf16x8*)&Bhs[s][(ct * 64 + lane) * 8];
        bf16x8 bl = *(const bf16x8*)&Bls[s][(ct * 64 + lane) * 8];
        acc[0][c] = __builtin_amdgcn_mfma_f32_16x16x32_bf16(a0, bh, acc[0][c], 0, 0, 0);
        acc[0][c] = __builtin_amdgcn_mfma_f32_16x16x32_bf16(a0, bl, acc[0][c], 0, 0, 0);
        acc[1][c] = __builtin_amdgcn_mfma_f32_16x16x32_bf16(a1, bh, acc[1][c], 0, 0, 0);
        acc[1][c] = __builtin_amdgcn_mfma_f32_16x16x32_bf16(a1, bl, acc[1][c], 0, 0, 0);
      }
    }
    __syncthreads();
  }

  // ---- epilogue: bf16 mirror only (slot c = output col colbase+c) ----
  const int coln = lane & 15;
  const int rown = (lane >> 4) * 4;
  const int colbase = ch * 64 + coln * 4;
  const float4 bv = *(const float4*)(bias + colbase);
#pragma unroll
  for (int r = 0; r < 2; ++r) {
#pragma unroll
    for (int reg = 0; reg < 4; ++reg) {
      int row = m0 + rgrp * 32 + r * 16 + rown + reg;
      if (row < M) {
        ushort4 hb;
        hb.x = f2bf(fmaxf(acc[r][0][reg] + bv.x, 0.f));
        hb.y = f2bf(fmaxf(acc[r][1][reg] + bv.y, 0.f));
        hb.z = f2bf(fmaxf(acc[r][2][reg] + bv.z, 0.f));
        hb.w = f2bf(fmaxf(acc[r][3][reg] + bv.w, 0.f));
        *(ushort4*)&xb_out[(size_t)row * DH + colbase] = hb;
      }
    }
  }
}

// ---------------------------------------------------------------------------
// FUSED aggregate + GIN MLP pair (R11 proven gather form). R16: B staging
// via uint4 loads -> ds_write (global_load_lds removed, see head comment).
// Each wave aggregates 16 of the block's 64 nodes directly into Hb (lane
// owns dims 2l, 2l+1); stage 1 reads A-fragments straight from Hb; stage 2
// overwrites Hb with h (barrier-ordered). B1(0) loads issued before gather.
// Epilogue: layer 1 -> xb_out bf16; layer 2 -> fused tail (z + BN partials).
// LDS: 8 + 8 + 17.4 = 33.4 KB -> 4 blocks/CU.
// ---------------------------------------------------------------------------
__global__ __launch_bounds__(256) void gemm_gin_fused(
    const unsigned short* __restrict__ xb_in,
    const int* __restrict__ rs, const int* __restrict__ esrc,
    const unsigned short* __restrict__ B1h, const unsigned short* __restrict__ B1l,
    const float* __restrict__ b1,
    const unsigned short* __restrict__ B2h, const unsigned short* __restrict__ B2l,
    const float* __restrict__ b2,
    unsigned short* __restrict__ xb_out, int M,
    const float* __restrict__ tw, const float* __restrict__ tb,
    float* __restrict__ z, float* __restrict__ red) {
  constexpr int KSTEPS = 4;   // K=128, BK=32
  constexpr int HSTR = 136;   // 128 + 8 pad
  __shared__ __align__(16) unsigned short Bhs[4096];       // 8 KB
  __shared__ __align__(16) unsigned short Bls[4096];       // 8 KB
  __shared__ __align__(16) unsigned short Hb[64 * HSTR];   // 17.4 KB (y, then h)

  const int tid = threadIdx.x;
  const int wave = tid >> 6;
  const int lane = tid & 63;
  const int m0 = blockIdx.x * 64;

  const int rgrp = wave & 1;
  const int ch = wave >> 1;
  const int coln = lane & 15;
  const int rown = (lane >> 4) * 4;
  const int colbase = ch * 64 + coln * 4;

  // load B tile for kstep into registers (4 uint4)
  auto loadB = [&](const unsigned short* Bh, const unsigned short* Bl, int ks,
                   uint4& h0, uint4& h1, uint4& l0, uint4& l1) {
    const unsigned short* sh = Bh + (size_t)ks * 4096 + wave * 1024;
    const unsigned short* sl = Bl + (size_t)ks * 4096 + wave * 1024;
    h0 = *(const uint4*)(sh + lane * 8);
    h1 = *(const uint4*)(sh + 512 + lane * 8);
    l0 = *(const uint4*)(sl + lane * 8);
    l1 = *(const uint4*)(sl + 512 + lane * 8);
  };
  auto writeB = [&](uint4 h0, uint4 h1, uint4 l0, uint4 l1) {
    *(uint4*)&Bhs[wave * 1024 + lane * 8] = h0;
    *(uint4*)&Bhs[wave * 1024 + 512 + lane * 8] = h1;
    *(uint4*)&Bls[wave * 1024 + lane * 8] = l0;
    *(uint4*)&Bls[wave * 1024 + 512 + lane * 8] = l1;
  };

  // ---- B1(0) loads issued before the gather phase (latency hides under it) ----
  uint4 pbh0, pbh1, pbl0, pbl1;
  loadB(B1h, B1l, 0, pbh0, pbh1, pbl0, pbl1);

  // ================= aggregation phase: y -> Hb (bf16) =================
  // Wave w aggregates local rows w*16..w*16+15; lane owns dims (2l, 2l+1).
  {
    const unsigned* xb2 = (const unsigned*)xb_in;  // 2 bf16 per uint
    for (int i = 0; i < 16; ++i) {
      int lrow = wave * 16 + i;
      int node = m0 + lrow;
      float2 acc2 = {0.f, 0.f};
      if (node < M) {
        unsigned vs = xb2[(size_t)node * 64 + lane];
        acc2.x = __uint_as_float(vs << 16);
        acc2.y = __uint_as_float(vs & 0xFFFF0000u);
        int j = rs[node];
        int end = rs[node + 1];
        for (; j + 8 <= end; j += 8) {
          int4 ia = *(const int4*)&esrc[j];
          int4 ib = *(const int4*)&esrc[j + 4];
          unsigned v0 = xb2[(size_t)ia.x * 64 + lane];
          unsigned v1 = xb2[(size_t)ia.y * 64 + lane];
          unsigned v2 = xb2[(size_t)ia.z * 64 + lane];
          unsigned v3 = xb2[(size_t)ia.w * 64 + lane];
          unsigned v4 = xb2[(size_t)ib.x * 64 + lane];
          unsigned v5 = xb2[(size_t)ib.y * 64 + lane];
          unsigned v6 = xb2[(size_t)ib.z * 64 + lane];
          unsigned v7 = xb2[(size_t)ib.w * 64 + lane];
          acc2.x += ((__uint_as_float(v0 << 16) + __uint_as_float(v1 << 16)) +
                     (__uint_as_float(v2 << 16) + __uint_as_float(v3 << 16))) +
                    ((__uint_as_float(v4 << 16) + __uint_as_float(v5 << 16)) +
                     (__uint_as_float(v6 << 16) + __uint_as_float(v7 << 16)));
          acc2.y += ((__uint_as_float(v0 & 0xFFFF0000u) + __uint_as_float(v1 & 0xFFFF0000u)) +
                     (__uint_as_float(v2 & 0xFFFF0000u) + __uint_as_float(v3 & 0xFFFF0000u))) +
                    ((__uint_as_float(v4 & 0xFFFF0000u) + __uint_as_float(v5 & 0xFFFF0000u)) +
                     (__uint_as_float(v6 & 0xFFFF0000u) + __uint_as_float(v7 & 0xFFFF0000u)));
        }
        if (j < end) {  // exactly one aligned 4-batch remains
          int4 ia = *(const int4*)&esrc[j];
          unsigned v0 = xb2[(size_t)ia.x * 64 + lane];
          unsigned v1 = xb2[(size_t)ia.y * 64 + lane];
          unsigned v2 = xb2[(size_t)ia.z * 64 + lane];
          unsigned v3 = xb2[(size_t)ia.w * 64 + lane];
          acc2.x += (__uint_as_float(v0 << 16) + __uint_as_float(v1 << 16)) +
                    (__uint_as_float(v2 << 16) + __uint_as_float(v3 << 16));
          acc2.y += (__uint_as_float(v0 & 0xFFFF0000u) + __uint_as_float(v1 & 0xFFFF0000u)) +
                    (__uint_as_float(v2 & 0xFFFF0000u) + __uint_as_float(v3 & 0xFFFF0000u));
        }
      }
      // lane l owns dims 2l,2l+1 -> 4-B aligned LDS write, 2-way bank alias
      *(unsigned*)&Hb[lrow * HSTR + 2 * lane] =
          (unsigned)f2bf(acc2.x) | ((unsigned)f2bf(acc2.y) << 16);
    }
  }

  f32x4 acc[2][4];
#pragma unroll
  for (int r = 0; r < 2; ++r)
#pragma unroll
    for (int c = 0; c < 4; ++c) acc[r][c] = (f32x4){0.f, 0.f, 0.f, 0.f};

  // ================= stage 1: h = relu(y @ W1 + b1) =================
  for (int ks = 0; ks < KSTEPS; ++ks) {
    writeB(pbh0, pbh1, pbl0, pbl1);        // publish B(ks) to LDS
    if (ks + 1 < KSTEPS) loadB(B1h, B1l, ks + 1, pbh0, pbh1, pbl0, pbl1);
    else loadB(B2h, B2l, 0, pbh0, pbh1, pbl0, pbl1);  // prefetch stage-2 B(0)
    __syncthreads();  // iter 0: publishes Hb (y) + B(0)
    bf16x8 a0 = *(const bf16x8*)&Hb[(rgrp * 32 + (lane & 15)) * HSTR + ks * 32 + (lane >> 4) * 8];
    bf16x8 a1 = *(const bf16x8*)&Hb[(rgrp * 32 + 16 + (lane & 15)) * HSTR + ks * 32 + (lane >> 4) * 8];
#pragma unroll
    for (int c = 0; c < 4; ++c) {
      int ct = ch * 4 + c;
      bf16x8 bh = *(const bf16x8*)&Bhs[(ct * 64 + lane) * 8];
      bf16x8 bl = *(const bf16x8*)&Bls[(ct * 64 + lane) * 8];
      acc[0][c] = __builtin_amdgcn_mfma_f32_16x16x32_bf16(a0, bh, acc[0][c], 0, 0, 0);
      acc[0][c] = __builtin_amdgcn_mfma_f32_16x16x32_bf16(a0, bl, acc[0][c], 0, 0, 0);
      acc[1][c] = __builtin_amdgcn_mfma_f32_16x16x32_bf16(a1, bh, acc[1][c], 0, 0, 0);
      acc[1][c] = __builtin_amdgcn_mfma_f32_16x16x32_bf16(a1, bl, acc[1][c], 0, 0, 0);
    }
    __syncthreads();
  }

  // ---- h -> Hb (overwrites y; all stage-1 reads completed at last barrier) ----
  {
    const float4 bv = *(const float4*)(b1 + colbase);
#pragma unroll
    for (int r = 0; r < 2; ++r) {
#pragma unroll
      for (int reg = 0; reg < 4; ++reg) {
        int lrow = rgrp * 32 + r * 16 + rown + reg;
        ushort4 hb;
        hb.x = f2bf(fmaxf(acc[r][0][reg] + bv.x, 0.f));
        hb.y = f2bf(fmaxf(acc[r][1][reg] + bv.y, 0.f));
        hb.z = f2bf(fmaxf(acc[r][2][reg] + bv.z, 0.f));
        hb.w = f2bf(fmaxf(acc[r][3][reg] + bv.w, 0.f));
        *(ushort4*)&Hb[lrow * HSTR + colbase] = hb;
      }
    }
#pragma unroll
    for (int r = 0; r < 2; ++r)
#pragma unroll
      for (int c = 0; c < 4; ++c) acc[r][c] = (f32x4){0.f, 0.f, 0.f, 0.f};
  }

  // ================= stage 2: out = h @ W2 + b2 =================
  for (int ks = 0; ks < KSTEPS; ++ks) {
    writeB(pbh0, pbh1, pbl0, pbl1);        // publish B2(ks)
    if (ks + 1 < KSTEPS) loadB(B2h, B2l, ks + 1, pbh0, pbh1, pbl0, pbl1);
    __syncthreads();  // first iter: also publishes h to all waves
    bf16x8 a0 = *(const bf16x8*)&Hb[(rgrp * 32 + (lane & 15)) * HSTR + ks * 32 + (lane >> 4) * 8];
    bf16x8 a1 = *(const bf16x8*)&Hb[(rgrp * 32 + 16 + (lane & 15)) * HSTR + ks * 32 + (lane >> 4) * 8];
#pragma unroll
    for (int c = 0; c < 4; ++c) {
      int ct = ch * 4 + c;
      bf16x8 bh = *(const bf16x8*)&Bhs[(ct * 64 + lane) * 8];
      bf16x8 bl = *(const bf16x8*)&Bls[(ct * 64 + lane) * 8];
      acc[0][c] = __builtin_amdgcn_mfma_f32_16x16x32_bf16(a0, bh, acc[0][c], 0, 0, 0);
      acc[0][c] = __builtin_amdgcn_mfma_f32_16x16x32_bf16(a0, bl, acc[0][c], 0, 0, 0);
      acc[1][c] = __builtin_amdgcn_mfma_f32_16x16x32_bf16(a1, bh, acc[1][c], 0, 0, 0);
      acc[1][c] = __builtin_amdgcn_mfma_f32_16x16x32_bf16(a1, bl, acc[1][c], 0, 0, 0);
    }
    __syncthreads();  // last iter: Hb reads complete -> safe to reuse below
  }

  const float4 bv = *(const float4*)(b2 + colbase);

  if (tw == nullptr) {
    // ---- layer-1 epilogue: bf16 features only ----
#pragma unroll
    for (int r = 0; r < 2; ++r) {
#pragma unroll
      for (int reg = 0; reg < 4; ++reg) {
        int row = m0 + rgrp * 32 + r * 16 + rown + reg;
        if (row < M) {
          ushort4 hb;
          hb.x = f2bf(acc[r][0][reg] + bv.x);
          hb.y = f2bf(acc[r][1][reg] + bv.y);
          hb.z = f2bf(acc[r][2][reg] + bv.z);
          hb.w = f2bf(acc[r][3][reg] + bv.w);
          *(ushort4*)&xb_out[(size_t)row * DH + colbase] = hb;
        }
      }
    }
  } else {
    // ---- layer-2 fused-tail epilogue: z + BN partials, no feature write ----
    float* zpart = (float*)Hb;  // 64 x 33 fp32 = 8.4 KB (fits in 17.4 KB)
    const float4 tw4 = *(const float4*)(tw + colbase);
#pragma unroll
    for (int r = 0; r < 2; ++r) {
#pragma unroll
      for (int reg = 0; reg < 4; ++reg) {
        int lrow = rgrp * 32 + r * 16 + rown + reg;
        float4 v;
        v.x = acc[r][0][reg] + bv.x;
        v.y = acc[r][1][reg] + bv.y;
        v.z = acc[r][2][reg] + bv.z;
        v.w = acc[r][3][reg] + bv.w;
        zpart[lrow * 33 + ch * 16 + coln] =
            v.x * tw4.x + v.y * tw4.y + v.z * tw4.z + v.w * tw4.w;
      }
    }
    __syncthreads();
    if (tid < 64) {
      int row = m0 + tid;
      float s = 0.f;
#pragma unroll
      for (int k = 0; k < 32; ++k) s += zpart[tid * 33 + k];
      float zv = s + tb[0];
      bool valid = row < M;
      if (valid) z[row] = zv;
      float a = valid ? zv : 0.f;
      float q = valid ? zv * zv : 0.f;
#pragma unroll
      for (int m = 32; m; m >>= 1) {
        a += __shfl_xor(a, m);
        q += __shfl_xor(q, m);
      }
      if (tid == 0) {
        atomicAdd(&red[0], a);
        atomicAdd(&red[1], q);
      }
    }
  }
}

// ---------------------------------------------------------------------------
// CSR build: exclusive scan over PADDED degrees (pad to multiple of 4 so the
// gather's index loads are aligned int4 and the edge loop has no tails).
// Pad slots point at dummy node N_NODES whose feature rows are zeroed.
// scan_partials fused into add_offsets_pad (R15).
// ---------------------------------------------------------------------------
__global__ __launch_bounds__(256) void scan_block(const int* __restrict__ cnt,
                                                  int* __restrict__ rs,
                                                  int* __restrict__ partials,
                                                  float* __restrict__ red) {
  int t = threadIdx.x;
  if (blockIdx.x == 0 && t == 0) { red[0] = 0.f; red[1] = 0.f; }
  int i = blockIdx.x * 256 + t;
  int v = (i < N_NODES) ? ((cnt[i] + 3) & ~3) : 0;   // padded degree
  __shared__ int s[256];
  s[t] = v;
  __syncthreads();
#pragma unroll
  for (int off = 1; off < 256; off <<= 1) {
    int add = (t >= off) ? s[t - off] : 0;
    __syncthreads();
    s[t] += add;
    __syncthreads();
  }
  if (i < N_NODES) rs[i] = s[t] - v;
  if (t == 255) partials[blockIdx.x] = s[255];
}

// add block offsets (self-computed prefix of raw partials) + write pad slots
// + zero cnt (cursor) — merged. Pad bounds derive locally.
__global__ __launch_bounds__(256) void add_offsets_pad(
    int* __restrict__ rs, const int* __restrict__ partials,
    int* __restrict__ cnt, int* __restrict__ esrc) {
  __shared__ int s[256];
  int t = threadIdx.x;
  s[t] = (t < (int)blockIdx.x) ? partials[t] : 0;   // blockIdx.x <= 195 < 256
  __syncthreads();
  for (int off = 128; off; off >>= 1) {
    if (t < off) s[t] += s[t + off];
    __syncthreads();
  }
  int base = s[0];
  int i = blockIdx.x * 256 + t;
  if (i >= N_NODES) return;
  int v = rs[i] + base;
  rs[i] = v;
  int d = cnt[i];
  cnt[i] = 0;
  int pe = v + ((d + 3) & ~3);
  if (i == N_NODES - 1) rs[N_NODES] = pe;
  for (int k = v + d; k < pe; ++k) esrc[k] = N_NODES;
}

// ---------------------------------------------------------------------------
// BN apply: out = (z - mu) * rsqrt(var + eps) * gamma + beta.
// ---------------------------------------------------------------------------
__global__ __launch_bounds__(256) void bn2(const float* __restrict__ z,
                                           const float* __restrict__ red,
                                           const float* __restrict__ gamma,
                                           const float* __restrict__ beta,
                                           float* __restrict__ out) {
  int i = blockIdx.x * 256 + threadIdx.x;
  if (i >= N_NODES) return;
  float mu = red[0] * (1.0f / N_NODES);
  float var = red[1] * (1.0f / N_NODES) - mu * mu;
  out[i] = (z[i] - mu) * rsqrtf(var + BN_EPS) * gamma[0] + beta[0];
}

// ---------------------------------------------------------------------------
extern "C" void kernel_launch(void* const* d_in, const int* in_sizes, int n_in,
                              void* d_out, int out_size, void* d_ws, size_t ws_size,
                              hipStream_t stream) {
  const float* feature = (const float*)d_in[0];
  const int* eidx = (const int*)d_in[1];
  const float* head_W = (const float*)d_in[2];
  const float* head_b = (const float*)d_in[3];
  const float* gin_W1 = (const float*)d_in[4];
  const float* gin_b1 = (const float*)d_in[5];
  const float* lin_W1 = (const float*)d_in[6];
  const float* lin_b1 = (const float*)d_in[7];
  const float* gin_W2 = (const float*)d_in[8];
  const float* gin_b2 = (const float*)d_in[9];
  const float* lin_W2 = (const float*)d_in[10];
  const float* lin_b2 = (const float*)d_in[11];
  const float* tail_W = (const float*)d_in[12];
  const float* tail_b = (const float*)d_in[13];
  const float* bn_gamma = (const float*)d_in[14];
  const float* bn_beta = (const float*)d_in[15];

  float* z = (float*)d_ws;                       // N
  float* red = z + N_NODES;                      // 2 floats
  int* row_start = (int*)(red + 2);              // N+1
  int* cnt = row_start + (N_NODES + 1);          // N
  int* partials = cnt + N_NODES;                 // 256
  int* esrc = (int*)(((uintptr_t)(partials + 256) + 15) & ~(uintptr_t)15);
  // padded CSR: at most E + 3*N = 750000 slots
  unsigned short* wp =
      (unsigned short*)(((uintptr_t)(esrc + 760000) + 15) & ~(uintptr_t)15);
  unsigned short* hH = wp;            // head hi: 512*128
  unsigned short* hL = hH + 65536;    // head lo
  unsigned short* g1H = hL + 65536;   // 128*128 each below
  unsigned short* g1L = g1H + 16384;
  unsigned short* l1H = g1L + 16384;
  unsigned short* l1L = l1H + 16384;
  unsigned short* g2H = l1L + 16384;
  unsigned short* g2L = g2H + 16384;
  unsigned short* l2H = g2L + 16384;
  unsigned short* l2L = l2H + 16384;
  unsigned short* xb0 = l2L + 16384;             // bf16 features A, (N+1) x 128
  unsigned short* xb1 = xb0 + (size_t)(N_NODES + 1) * DH;  // features B (ping-pong)

  const int gin_grid = (N_NODES + 63) / 64;      // 782 (BM=64)
  const int edge_grid = (N_EDGES + 255) / 256;   // 2344

  // ---- zero degree counters ----
  hipMemsetAsync(cnt, 0, N_NODES * sizeof(int), stream);

  // ---- weight pre-split + degree count + both dummy-row zeros: one launch ----
  convert_W5_count<<<512 + edge_grid, 256, 0, stream>>>(
      head_W, gin_W1, lin_W1, gin_W2, lin_W2, hH, hL, g1H, g1L, l1H, l1L,
      g2H, g2L, l2H, l2L, eidx, cnt,
      (unsigned*)(xb0 + (size_t)N_NODES * DH),
      (unsigned*)(xb1 + (size_t)N_NODES * DH));

  // ---- CSR build over padded degrees (2 launches; prefix fused into 2nd) ----
  scan_block<<<SCAN_BLOCKS, 256, 0, stream>>>(cnt, row_start, partials, red);
  add_offsets_pad<<<SCAN_BLOCKS, 256, 0, stream>>>(row_start, partials, cnt, esrc);

  // ---- head GEMM (fused with fill_csr; writes xb0) ----
  gemm_head_fill<<<HEAD_GRID + edge_grid, 256, 0, stream>>>(
      feature, hH, hL, head_b, xb0, N_NODES, eidx, row_start, cnt, esrc);

  // ---- layer 1: fused aggregate + GIN MLP pair (xb0 -> xb1) ----
  gemm_gin_fused<<<gin_grid, 256, 0, stream>>>(
      xb0, row_start, esrc, g1H, g1L, gin_b1, l1H, l1L, lin_b1,
      xb1, N_NODES, nullptr, nullptr, nullptr, nullptr);

  // ---- layer 2: fused aggregate + GIN MLP pair + tail (xb1 -> z, red) ----
  gemm_gin_fused<<<gin_grid, 256, 0, stream>>>(
      xb1, row_start, esrc, g2H, g2L, gin_b2, l2H, l2L, lin_b2,
      nullptr, N_NODES, tail_W, tail_b, z, red);

  // ---- batchnorm apply ----
  bn2<<<(N_NODES + 255) / 256, 256, 0, stream>>>(z, red, bn_gamma, bn_beta, (float*)d_out);
}